// Round 11
// baseline (422.148 us; speedup 1.0000x reference)
//
#include <hip/hip_runtime.h>
#include <math.h>

#define T_TOKENS 32768
#define HIDDEN   2048
#define NE       8
#define BLOCK    1024
#define WPB      16                     // waves per block
#define GRID     256                    // 1 block/CU; 128 contiguous tokens/block
#define GPW      4                      // groups (of 2 tokens) per wave
#define NSTEP    32                     // 4 groups x 8 chunks

// ws layout (floats): [0..7]=importance sums, [16]=sum(lse^2); load via finalize histogram
__global__ __launch_bounds__(BLOCK, 4) void router_main(
    const float* __restrict__ x, const float* __restrict__ W,
    float* __restrict__ out, float* __restrict__ ws)
{
    __shared__ float w_lds[NE * HIDDEN];        // 64 KiB
    __shared__ float stage[WPB][2][512];        // 64 KiB: per-wave 2-deep ring, 2 KiB/slot
    __shared__ float s_acc[17];                 // total ~131 KiB (round-6-proven size)

    // Stage W into LDS: 16384 floats, 1024 threads * float4
#pragma unroll
    for (int j = 0; j < (NE * HIDDEN) / (BLOCK * 4); ++j) {
        const int idx = 4 * (threadIdx.x + BLOCK * j);
        *(float4*)&w_lds[idx] = *(const float4*)&W[idx];
    }
    if (threadIdx.x < 17) s_acc[threadIdx.x] = 0.0f;
    __syncthreads();

    const int lane = threadIdx.x & 63;
    const int wid  = threadIdx.x >> 6;
    const int tw   = blockIdx.x * (WPB * 8) + wid * 8;   // wave's 8 contiguous tokens

    const float* xb = x + (size_t)tw * HIDDEN + lane * 4;

    // step s: group g=s>>3 (tokens tw+2g, tw+2g+1), chunk c=s&7; ring slot s&1.
    // LDS dest is linear (wave base + lane*16B), matching the lane*4-float reads.
    auto issue = [&](int s) {
        const float* g = xb + (size_t)((s >> 3) * 2) * HIDDEN + (s & 7) * 256;
        float* dst = &stage[wid][s & 1][0];
        __builtin_amdgcn_global_load_lds(
            (const __attribute__((address_space(1))) void*)g,
            (__attribute__((address_space(3))) void*)dst, 16, 0, 0);
        __builtin_amdgcn_global_load_lds(
            (const __attribute__((address_space(1))) void*)(g + HIDDEN),
            (__attribute__((address_space(3))) void*)(dst + 256), 16, 0, 0);
    };

    issue(0);

    float imp_acc = 0.0f, z_acc = 0.0f;

#pragma unroll
    for (int i = 0; i < GPW; ++i) {
        const int t0 = tw + 2 * i;

        float v[16];
#pragma unroll
        for (int k = 0; k < 16; ++k) v[k] = 0.0f;

#pragma unroll
        for (int c = 0; c < 8; ++c) {
            const int s = i * 8 + c;

            // 1) issue next batch FIRST into the other slot (consumed at step
            //    s-1; its ds_reads retired — their FMA consumers executed).
            if (s + 1 < NSTEP) issue(s + 1);

            // 2) W fragments: lgkm-tracked, overlap the vmcnt wait below.
            float4 wv[NE];
#pragma unroll
            for (int e = 0; e < NE; ++e)
                wv[e] = *(const float4*)&w_lds[e * HIDDEN + c * 256 + lane * 4];

            // 3) counted wait for batch s. FIFO ages at this point:
            //    c==0,i>0: [batch s(2), stores(2), batch s+1(2)] -> vmcnt(4)
            //    steady:   [batch s(2), batch s+1(2)]            -> vmcnt(2)
            //    last:     [batch s(2)]                          -> vmcnt(0)
            if (s == NSTEP - 1)      asm volatile("s_waitcnt vmcnt(0)" ::: "memory");
            else if (c == 0 && i)    asm volatile("s_waitcnt vmcnt(4)" ::: "memory");
            else                     asm volatile("s_waitcnt vmcnt(2)" ::: "memory");

            // 4) consume
            const float* xs = &stage[wid][s & 1][0];
            const float4 xv0 = *(const float4*)&xs[lane * 4];
            const float4 xv1 = *(const float4*)&xs[256 + lane * 4];

#pragma unroll
            for (int e = 0; e < NE; ++e) {
                v[e]      = fmaf(xv0.x, wv[e].x, fmaf(xv0.y, wv[e].y,
                            fmaf(xv0.z, wv[e].z, fmaf(xv0.w, wv[e].w, v[e]))));
                v[NE + e] = fmaf(xv1.x, wv[e].x, fmaf(xv1.y, wv[e].y,
                            fmaf(xv1.z, wv[e].z, fmaf(xv1.w, wv[e].w, v[NE + e]))));
            }
        }

        // ---- value-pairing butterfly: 16 values x 64 lanes -> lane l holds
        // value (l&15): token slot (l>>3)&1, expert l&7, summed over the wave.
#pragma unroll
        for (int step = 0; step < 4; ++step) {
            const int m = 1 << step;
            const int n = 16 >> step;
            const bool hi = (lane & m) != 0;
#pragma unroll
            for (int k = 0; k < n / 2; ++k) {
                const float a = v[2 * k], b = v[2 * k + 1];
                const float keep = hi ? b : a;
                const float send = hi ? a : b;
                v[k] = keep + __shfl_xor(send, m, 64);
            }
        }
        v[0] += __shfl_xor(v[0], 16, 64);
        v[0] += __shfl_xor(v[0], 32, 64);

        // ---- wave-parallel epilogue (no LDS, no atomics in the loop)
        const int e  = lane & 7;
        const int tk = t0 + ((lane >> 3) & 1);
        const float lg = v[0];

        float mx = lg;
#pragma unroll
        for (int m2 = 1; m2 <= 4; m2 <<= 1) mx = fmaxf(mx, __shfl_xor(mx, m2, 64));
        const float p = __expf(lg - mx);
        float sm = p;
#pragma unroll
        for (int m2 = 1; m2 <= 4; m2 <<= 1) sm += __shfl_xor(sm, m2, 64);
        const float inv = 1.0f / sm;
        const float lse = mx + __logf(sm);
        const float prob = p * inv;

        // top-1 (lower index wins ties)
        float bv = prob; int be = e;
#pragma unroll
        for (int m2 = 1; m2 <= 4; m2 <<= 1) {
            const float ov = __shfl_xor(bv, m2, 64);
            const int   oe = __shfl_xor(be, m2, 64);
            if (ov > bv || (ov == bv && oe < be)) { bv = ov; be = oe; }
        }
        // top-2: exclude be
        float cv = (e == be) ? -1.0f : prob; int ce = e;
#pragma unroll
        for (int m2 = 1; m2 <= 4; m2 <<= 1) {
            const float ov = __shfl_xor(cv, m2, 64);
            const int   oe = __shfl_xor(ce, m2, 64);
            if (ov > cv || (ov == cv && oe < ce)) { cv = ov; ce = oe; }
        }

        if (lane < 16) {
            imp_acc += prob;                           // per-(slot,expert) register sum
            if (e == 0) {                              // lanes 0 (t0) and 8 (t0+1)
                const float denom = fmaxf(bv + cv, 1e-9f);
                float2 ex = make_float2((float)be, (float)ce);
                float2 sc = make_float2(bv / denom, cv / denom);
                *(float2*)&out[2 * tk] = ex;
                *(float2*)&out[2 * T_TOKENS + 2 * tk] = sc;
                z_acc += lse * lse;
            }
        }
    }

    // ---- end-of-kernel flush
    if (lane < 16) atomicAdd(&s_acc[lane & 7], imp_acc);
    if (lane == 0 || lane == 8) atomicAdd(&s_acc[16], z_acc);
    __syncthreads();
    if (threadIdx.x < 8) atomicAdd(&ws[threadIdx.x], s_acc[threadIdx.x]);
    if (threadIdx.x == 16) atomicAdd(&ws[16], s_acc[16]);
}

__global__ void router_finalize(const float* __restrict__ ws, float* __restrict__ out)
{
    __shared__ float h[NE];
    const int tid = threadIdx.x;
    if (tid < NE) h[tid] = 0.0f;
    __syncthreads();

    // Top-1 histogram from the expert indices kernel 1 already wrote.
    float cnt[NE];
#pragma unroll
    for (int k = 0; k < NE; ++k) cnt[k] = 0.0f;
    for (int t = tid; t < T_TOKENS; t += 256) {
        const int e = (int)out[2 * t];
#pragma unroll
        for (int k = 0; k < NE; ++k) cnt[k] += (e == k) ? 1.0f : 0.0f;
    }
#pragma unroll
    for (int k = 0; k < NE; ++k) atomicAdd(&h[k], cnt[k]);
    __syncthreads();

    if (tid == 0) {
        float impsum = 0.0f, loadsum = 0.0f;
#pragma unroll
        for (int e = 0; e < NE; ++e) { impsum += ws[e]; loadsum += h[e]; }
        impsum  = fmaxf(impsum, 1e-9f);
        loadsum = fmaxf(loadsum, 1e-9f);
        float lb = 0.0f;
#pragma unroll
        for (int e = 0; e < NE; ++e)
            lb += (ws[e] / impsum) * (h[e] / loadsum);
        lb *= (float)(NE * NE) * 0.01f;                    // NUM_EXPERTS^2 * LB_LOSS_COEF
        const float z = ws[16] / (float)T_TOKENS * 0.001f; // mean(lse^2) * Z_LOSS_COEF
        out[4 * T_TOKENS + 0] = z;   // 131072
        out[4 * T_TOKENS + 1] = lb;  // 131073
    }
}

extern "C" void kernel_launch(void* const* d_in, const int* in_sizes, int n_in,
                              void* d_out, int out_size, void* d_ws, size_t ws_size,
                              hipStream_t stream)
{
    const float* x = (const float*)d_in[0];
    const float* W = (const float*)d_in[1];
    float* out = (float*)d_out;
    float* ws  = (float*)d_ws;

    hipMemsetAsync(ws, 0, 17 * sizeof(float), stream);
    router_main<<<GRID, BLOCK, 0, stream>>>(x, W, out, ws);
    router_finalize<<<1, 256, 0, stream>>>(ws, out);
}